// Round 27
// baseline (285.669 us; speedup 1.0000x reference)
//
#include <hip/hip_runtime.h>

typedef __attribute__((ext_vector_type(8))) short bf16x8;
typedef __attribute__((ext_vector_type(4))) float f32x4;

__device__ __forceinline__ unsigned short f2bf(float f) {
  unsigned int u = __float_as_uint(f);
  u += 0x7FFF + ((u >> 16) & 1);
  return (unsigned short)(u >> 16);
}

__device__ __forceinline__ void gload_lds16(const void* g, void* l) {
  __builtin_amdgcn_global_load_lds(
      (const __attribute__((address_space(1))) unsigned int*)g,
      (__attribute__((address_space(3))) unsigned int*)l,
      16, 0, 0);
}

#define MF(a, b, c) __builtin_amdgcn_mfma_f32_16x16x32_bf16((a), (b), (c), 0, 0, 0)
#define FENCE asm volatile("" ::: "memory")
#define BAR do { FENCE; __builtin_amdgcn_s_barrier(); FENCE; } while (0)

// ---------------------------------------------------------------------------
// fused cast fp32 -> bf16 for x, w_attn, w_proj in one sweep
// ---------------------------------------------------------------------------
__global__ void cast_all(const float* __restrict__ x,
                         const float* __restrict__ wa,
                         const float* __restrict__ wp,
                         unsigned short* __restrict__ xb,
                         unsigned short* __restrict__ wab,
                         unsigned short* __restrict__ wpb,
                         int n1, int n2, int n4) {
  int stride = gridDim.x * blockDim.x;
  for (int i = blockIdx.x * blockDim.x + threadIdx.x; i < n4; i += stride) {
    const float4* src;
    ushort4* dst;
    int j;
    if (i < n1)      { src = (const float4*)x,  dst = (ushort4*)xb,  j = i; }
    else if (i < n2) { src = (const float4*)wa, dst = (ushort4*)wab, j = i - n1; }
    else             { src = (const float4*)wp, dst = (ushort4*)wpb, j = i - n2; }
    float4 v = src[j];
    ushort4 o;
    o.x = f2bf(v.x); o.y = f2bf(v.y); o.z = f2bf(v.z); o.w = f2bf(v.w);
    dst[j] = o;
  }
}

// ---------------------------------------------------------------------------
// 128x(NF*64) 4-phase GEMM v7 (round-26: qkv 128.7us @ NF=3, 2 blocks/CU).
// v8 change: for EPI==1 (qkv, grid 32x32), bijective XCD column-group
// swizzle — XCD k owns bx in [4k,4k+4) x all 32 by, so its 4 B-panels
// (3MB) are L2-resident instead of each B-panel scattering across all 8
// XCDs' L2s (FETCH showed 3x HBM over-fetch -> exposed vmcnt latency).
// ---------------------------------------------------------------------------
template<int EPI, int NF>
__global__ __launch_bounds__(512, 2)
void gemm8p(const unsigned short* __restrict__ A,
            const unsigned short* __restrict__ Bw,
            float* __restrict__ Cf,
            unsigned short* __restrict__ Qo,
            unsigned short* __restrict__ Ko,
            unsigned short* __restrict__ Vo,
            int M, int N, int K, int Lseq) {
  __shared__ unsigned short Al[2][128 * 64];       // 2 x 16KB
  __shared__ unsigned short Bl[2][NF * 64 * 64];   // 2 x NF*8KB
  const int tid = threadIdx.x;
  const int lane = tid & 63, w = tid >> 6;
  const int wm = w >> 2, wn = w & 3;
  const int g4 = lane >> 4, r16 = lane & 15;

  int bxv, byv;
  if (EPI == 1) {
    // qkv grid is 32x32: id = by*32+bx; XCD k gets bx in [4k,4k+4)
    int id = blockIdx.y * 32 + blockIdx.x;
    int xcd = id & 7, idx = id >> 3;          // idx in [0,128)
    bxv = xcd * 4 + (idx >> 5);               // 4 columns per XCD
    byv = idx & 31;
  } else {
    bxv = blockIdx.x; byv = blockIdx.y;
  }
  const long arow0 = (long)byv * 128;
  const long brow0 = (long)bxv * (NF * 64);

#define VMNF                                                                  \
  do {                                                                        \
    if constexpr (NF == 3) asm volatile("s_waitcnt vmcnt(3)" ::: "memory");   \
    else                   asm volatile("s_waitcnt vmcnt(4)" ::: "memory");   \
  } while (0)

  auto lda = [&](int db, int mf, int ks) -> bf16x8 {
    return *(const bf16x8*)((const char*)&Al[db][0] +
                            ((wm * 64 + mf * 16 + r16) << 7) +
                            (((ks * 4 + g4) ^ (r16 & 7)) << 4));
  };
  auto ldb = [&](int db, int nf, int ks) -> bf16x8 {
    return *(const bf16x8*)((const char*)&Bl[db][0] +
                            ((wn * (NF * 16) + nf * 16 + r16) << 7) +
                            (((ks * 4 + g4) ^ (r16 & 7)) << 4));
  };
  auto stgA = [&](int db, int kt) {
#pragma unroll
    for (int c_ = 0; c_ < 2; ++c_) {
      int off_ = (c_ << 13) + (tid << 4);
      int row_ = off_ >> 7;
      int cbs_ = ((off_ >> 4) & 7) ^ (row_ & 7);
      gload_lds16(A + (arow0 + row_) * (long)K + (kt << 6) + cbs_ * 8,
                  (char*)&Al[db][0] + off_);
    }
  };
  auto stgB = [&](int db, int kt) {
#pragma unroll
    for (int c_ = 0; c_ < NF; ++c_) {
      int off_ = (c_ << 13) + (tid << 4);
      int row_ = off_ >> 7;
      int cbs_ = ((off_ >> 4) & 7) ^ (row_ & 7);
      gload_lds16(Bw + (brow0 + row_) * (long)K + (kt << 6) + cbs_ * 8,
                  (char*)&Bl[db][0] + off_);
    }
  };

  f32x4 acc[4][NF];
#pragma unroll
  for (int i = 0; i < 4; ++i)
#pragma unroll
    for (int j = 0; j < NF; ++j) acc[i][j] = (f32x4){0.f, 0.f, 0.f, 0.f};

  bf16x8 breg[NF][2];
  bf16x8 aX[2][2], aY[2][2];

  auto loadB = [&](int db) {
#pragma unroll
    for (int nf = 0; nf < NF; ++nf)
#pragma unroll
      for (int ks = 0; ks < 2; ++ks) breg[nf][ks] = ldb(db, nf, ks);
  };
  auto prefA = [&](bf16x8 (&dst)[2][2], int db, int q) {
#pragma unroll
    for (int mf = 0; mf < 2; ++mf)
#pragma unroll
      for (int ks = 0; ks < 2; ++ks) dst[mf][ks] = lda(db, 2 * q + mf, ks);
  };
  auto mfq = [&](int q, bf16x8 (&af)[2][2]) {
    __builtin_amdgcn_s_setprio(1);
#pragma unroll
    for (int mf = 0; mf < 2; ++mf)
#pragma unroll
      for (int nf = 0; nf < NF; ++nf) {
        acc[2 * q + mf][nf] = MF(af[mf][0], breg[nf][0], acc[2 * q + mf][nf]);
        acc[2 * q + mf][nf] = MF(af[mf][1], breg[nf][1], acc[2 * q + mf][nf]);
      }
    __builtin_amdgcn_s_setprio(0);
  };

  const int NT = K >> 6;
  stgB(0, 0); stgA(0, 0); stgB(1, 1);
  VMNF;
  BAR;
  loadB(0);
  prefA(aX, 0, 0);

  for (int i = 0; i < (NT >> 1); ++i) {
    const int t1 = 2 * i + 1;
    int t2 = 2 * i + 2; if (t2 > NT - 1) t2 = NT - 1;
    int t3 = 2 * i + 3; if (t3 > NT - 1) t3 = NT - 1;
    stgA(1, t1);
    BAR;
    mfq(0, aX);
    prefA(aY, 0, 1);
    BAR;
    stgB(0, t2);
    VMNF;
    BAR;
    mfq(1, aY);
    loadB(1);
    prefA(aX, 1, 0);
    BAR;
    stgA(0, t2);
    BAR;
    mfq(0, aX);
    prefA(aY, 1, 1);
    BAR;
    stgB(1, t3);
    VMNF;
    BAR;
    mfq(1, aY);
    loadB(0);
    prefA(aX, 0, 0);
    BAR;
  }
  asm volatile("s_waitcnt vmcnt(0)" ::: "memory");

  const float qscale = 0.08838834764831845f;  // 1/sqrt(128) folded into Q
#pragma unroll
  for (int mf = 0; mf < 4; ++mf) {
#pragma unroll
    for (int nf = 0; nf < NF; ++nf) {
#pragma unroll
      for (int i = 0; i < 4; ++i) {
        long row = arow0 + wm * 64 + mf * 16 + 4 * g4 + i;
        long col = brow0 + wn * (NF * 16) + nf * 16 + r16;
        float v = acc[mf][nf][i];
        if (EPI == 0) {
          Cf[row * N + col] = v;
        } else {
          int which = (int)(col >> 11);
          int h = ((int)col >> 7) & 15;
          int d = (int)col & 127;
          int b = (int)(row >> 11);
          int l = (int)row & 2047;
          long bhead = (long)(b * 16 + h);
          if (which == 0)
            Qo[(bhead * Lseq + l) * 128 + d] = f2bf(v * qscale);
          else if (which == 1)
            Ko[(bhead * Lseq + l) * 128 + d] = f2bf(v);
          else
            Vo[(bhead * 128 + d) * Lseq + l] = f2bf(v);
        }
      }
    }
  }
#undef VMNF
}

// ---------------------------------------------------------------------------
// Flash attention (causal) v6: round-12 dataflow + V-fragment hoist
// (measured: attn ~64us).
// ---------------------------------------------------------------------------
__global__ __launch_bounds__(256, 2)
void attn_fwd(const unsigned short* __restrict__ Q,
              const unsigned short* __restrict__ K,
              const unsigned short* __restrict__ Vt,
              unsigned short* __restrict__ Y, int L) {
  const int D = 128;
  const int id = blockIdx.x;
  const int g = id & 7, kk = id >> 3;
  const int bh = (g << 2) + (kk >> 5);
  const int qt = 31 - (kk & 31);
  const int tid = threadIdx.x, lane = tid & 63, w = tid >> 6;
  const int g4 = lane >> 4, r16 = lane & 15;
  const int q0 = qt * 64;

  __shared__ unsigned short Klds[2 * 64 * 128];
  __shared__ unsigned short Vlds[2 * 128 * 64];
  __shared__ unsigned short P[4][16][64];
  __shared__ float corrS[4][16];
  __shared__ float lrunS[4][16];

  const unsigned short* Qh = Q + (long)bh * L * D;
  const unsigned short* Kh = K + (long)bh * L * D;
  const unsigned short* Vh = Vt + (long)bh * D * L;

#define STAGE_TILE(kt_, buf_)                                                 \
  do {                                                                        \
    const int kbase_ = (kt_) * 64;                                            \
    _Pragma("unroll")                                                         \
    for (int r_ = 0; r_ < 4; ++r_) {                                          \
      int off_ = (tid << 4) + (r_ << 12);                                     \
      int krow_ = off_ >> 8, kcb_ = (off_ >> 4) & 15;                         \
      int kcbs_ = kcb_ ^ (krow_ & 7);                                         \
      gload_lds16(Kh + (long)(kbase_ + krow_) * 128 + kcbs_ * 8,              \
                  (char*)Klds + (buf_)*16384 + (w << 10) + (r_ << 12));       \
      int vrow_ = off_ >> 7, vcb_ = (off_ >> 4) & 7;                          \
      int vcbs_ = vcb_ ^ (vrow_ & 7);                                         \
      gload_lds16(Vh + (long)vrow_ * L + kbase_ + vcbs_ * 8,                  \
                  (char*)Vlds + (buf_)*16384 + (w << 10) + (r_ << 12));       \
    }                                                                         \
  } while (0)

  bf16x8 qf[4];
  {
    long qrow = q0 + 16 * w + r16;
#pragma unroll
    for (int ks = 0; ks < 4; ++ks)
      qf[ks] = *(const bf16x8*)(Qh + qrow * D + ks * 32 + g4 * 8);
  }
  f32x4 o[8];
#pragma unroll
  for (int j = 0; j < 8; ++j) o[j] = (f32x4){0.f, 0.f, 0.f, 0.f};
  float mrun = -1e30f, lrun = 0.f;
  const int qg = q0 + 16 * w + r16;
  char* Pl = (char*)&P[w][0][0];

  int cur = 0;
  STAGE_TILE(0, 0);

  for (int kt = 0; kt <= qt; ++kt) {
    if (kt < qt) {
      STAGE_TILE(kt + 1, cur ^ 1);
      asm volatile("s_waitcnt vmcnt(8)" ::: "memory");
    } else {
      asm volatile("s_waitcnt vmcnt(0)" ::: "memory");
    }
    __builtin_amdgcn_s_barrier();

    const char* Kl = (const char*)Klds + cur * 16384;
    const char* Vl = (const char*)Vlds + cur * 16384;

    f32x4 s[4];
#pragma unroll
    for (int nf = 0; nf < 4; ++nf) s[nf] = (f32x4){0.f, 0.f, 0.f, 0.f};
#pragma unroll
    for (int ks = 0; ks < 4; ++ks) {
#pragma unroll
      for (int nf = 0; nf < 4; ++nf) {
        int row = 16 * nf + r16;
        bf16x8 kf = *(const bf16x8*)(Kl + row * 256 +
                                     (((ks * 4 + g4) ^ (row & 7)) << 4));
        s[nf] = MF(kf, qf[ks], s[nf]);
      }
    }

    // V-hoist: issue all 16 V ds_reads now; softmax hides their latency.
    bf16x8 vfr[2][8];
#pragma unroll
    for (int ks2 = 0; ks2 < 2; ++ks2)
#pragma unroll
      for (int nf2 = 0; nf2 < 8; ++nf2) {
        int row = 16 * nf2 + r16;
        vfr[ks2][nf2] = *(const bf16x8*)(Vl + row * 128 +
                                         (((ks2 * 4 + g4) ^ (row & 7)) << 4));
      }

    const bool diag = (kt == qt);
    float rmax = -1e30f;
#pragma unroll
    for (int nf = 0; nf < 4; ++nf)
#pragma unroll
      for (int i = 0; i < 4; ++i) {
        float t = s[nf][i];
        if (diag && (kt * 64 + 16 * nf + 4 * g4 + i) > qg) t = -1e30f;
        s[nf][i] = t;
        rmax = fmaxf(rmax, t);
      }
    rmax = fmaxf(rmax, __shfl_xor(rmax, 16));
    rmax = fmaxf(rmax, __shfl_xor(rmax, 32));

    const bool full = __any(rmax > mrun + 8.0f);
    float corr = 1.f;
    if (full) {
      float mnew = fmaxf(mrun, rmax);
      corr = __expf(mrun - mnew);
      mrun = mnew;
      if (g4 == 0) corrS[w][r16] = corr;
    }

    float rs = 0.f;
#pragma unroll
    for (int nf = 0; nf < 4; ++nf) {
      float p0 = __expf(s[nf][0] - mrun);
      float p1 = __expf(s[nf][1] - mrun);
      float p2 = __expf(s[nf][2] - mrun);
      float p3 = __expf(s[nf][3] - mrun);
      rs += (p0 + p1) + (p2 + p3);
      ushort4 pw;
      pw.x = f2bf(p0); pw.y = f2bf(p1); pw.z = f2bf(p2); pw.w = f2bf(p3);
      *(ushort4*)(Pl + r16 * 128 + (((2 * nf + (g4 >> 1)) ^ (r16 & 7)) << 4) +
                  ((g4 & 1) << 3)) = pw;
    }
    rs += __shfl_xor(rs, 16);
    rs += __shfl_xor(rs, 32);
    lrun = lrun * corr + rs;

    if (full) {
#pragma unroll
      for (int i = 0; i < 4; ++i) {
        float cb = corrS[w][4 * g4 + i];
#pragma unroll
        for (int nf2 = 0; nf2 < 8; ++nf2) o[nf2][i] *= cb;
      }
    }

#pragma unroll
    for (int ks2 = 0; ks2 < 2; ++ks2) {
      bf16x8 pf = *(const bf16x8*)(Pl + r16 * 128 +
                                   (((ks2 * 4 + g4) ^ (r16 & 7)) << 4));
#pragma unroll
      for (int nf2 = 0; nf2 < 8; ++nf2)
        o[nf2] = MF(pf, vfr[ks2][nf2], o[nf2]);
    }
    FENCE;
    __builtin_amdgcn_s_barrier();
    cur ^= 1;
  }
#undef STAGE_TILE

  if (g4 == 0) lrunS[w][r16] = lrun;
  const int b = bh >> 4, h = bh & 15;
#pragma unroll
  for (int i = 0; i < 4; ++i) {
    float linv = 1.f / lrunS[w][4 * g4 + i];
#pragma unroll
    for (int nf2 = 0; nf2 < 8; ++nf2) {
      long row = (long)b * L + q0 + 16 * w + 4 * g4 + i;
      Y[row * 2048 + h * 128 + 16 * nf2 + r16] = f2bf(o[nf2][i] * linv);
    }
  }
}

// ---------------------------------------------------------------------------
extern "C" void kernel_launch(void* const* d_in, const int* in_sizes, int n_in,
                              void* d_out, int out_size, void* d_ws,
                              size_t ws_size, hipStream_t stream) {
  const float* x = (const float*)d_in[0];
  const float* wa = (const float*)d_in[1];
  const float* wp = (const float*)d_in[2];
  float* out = (float*)d_out;
  const int B = 2, L = 2048, C = 2048;
  const int M = B * L;  // 4096

  unsigned short* xb = (unsigned short*)d_ws;
  unsigned short* wab = xb + (size_t)M * C;
  unsigned short* wpb = wab + (size_t)3 * C * C;
  unsigned short* Qb = wpb + (size_t)C * C;
  unsigned short* Kb = Qb + (size_t)M * C;
  unsigned short* Vb = Kb + (size_t)M * C;
  unsigned short* Yb = Vb + (size_t)M * C;

  const int n1 = M * C / 4;
  const int n2 = n1 + 3 * C * C / 4;
  const int n4 = n2 + C * C / 4;
  cast_all<<<2048, 256, 0, stream>>>(x, wa, wp, xb, wab, wpb, n1, n2, n4);

  // qkv: 128x192 (NF=3), 80KB LDS, 2 blocks/CU, XCD column-group swizzle
  gemm8p<1, 3><<<dim3(3 * C / 192, M / 128), 512, 0, stream>>>(
      xb, wab, nullptr, Qb, Kb, Vb, M, 3 * C, C, L);

  // attn: QBLK=64, 4 waves, 1024 blocks (2 blocks/CU), V-hoist
  attn_fwd<<<1024, 256, 0, stream>>>(Qb, Kb, Vb, Yb, L);

  // proj: 128x256 (NF=4), grid 8x32 = 256 blocks = exactly 1 round
  gemm8p<0, 4><<<dim3(C / 256, M / 128), 512, 0, stream>>>(
      Yb, wpb, out, nullptr, nullptr, nullptr, M, C, C, L);
}

// Round 28
// 278.764 us; speedup vs baseline: 1.0248x; 1.0248x over previous
//
#include <hip/hip_runtime.h>

typedef __attribute__((ext_vector_type(8))) short bf16x8;
typedef __attribute__((ext_vector_type(4))) float f32x4;

__device__ __forceinline__ unsigned short f2bf(float f) {
  unsigned int u = __float_as_uint(f);
  u += 0x7FFF + ((u >> 16) & 1);
  return (unsigned short)(u >> 16);
}

__device__ __forceinline__ void gload_lds16(const void* g, void* l) {
  __builtin_amdgcn_global_load_lds(
      (const __attribute__((address_space(1))) unsigned int*)g,
      (__attribute__((address_space(3))) unsigned int*)l,
      16, 0, 0);
}

#define MF(a, b, c) __builtin_amdgcn_mfma_f32_16x16x32_bf16((a), (b), (c), 0, 0, 0)
#define FENCE asm volatile("" ::: "memory")
#define BAR do { FENCE; __builtin_amdgcn_s_barrier(); FENCE; } while (0)

// ---------------------------------------------------------------------------
// fused cast fp32 -> bf16 for x, w_attn, w_proj in one sweep
// ---------------------------------------------------------------------------
__global__ void cast_all(const float* __restrict__ x,
                         const float* __restrict__ wa,
                         const float* __restrict__ wp,
                         unsigned short* __restrict__ xb,
                         unsigned short* __restrict__ wab,
                         unsigned short* __restrict__ wpb,
                         int n1, int n2, int n4) {
  int stride = gridDim.x * blockDim.x;
  for (int i = blockIdx.x * blockDim.x + threadIdx.x; i < n4; i += stride) {
    const float4* src;
    ushort4* dst;
    int j;
    if (i < n1)      { src = (const float4*)x,  dst = (ushort4*)xb,  j = i; }
    else if (i < n2) { src = (const float4*)wa, dst = (ushort4*)wab, j = i - n1; }
    else             { src = (const float4*)wp, dst = (ushort4*)wpb, j = i - n2; }
    float4 v = src[j];
    ushort4 o;
    o.x = f2bf(v.x); o.y = f2bf(v.y); o.z = f2bf(v.z); o.w = f2bf(v.w);
    dst[j] = o;
  }
}

// ---------------------------------------------------------------------------
// 128x(NF*64) 4-phase GEMM v7 (round-26 verbatim: qkv 128.7us @ NF=3,
// 2 blocks/CU, default block mapping — the round-27 XCD column-group
// swizzle REPLICATED A per-XCD (FETCH 125->237MB, +7us) and is reverted).
// ---------------------------------------------------------------------------
template<int EPI, int NF>
__global__ __launch_bounds__(512, 2)
void gemm8p(const unsigned short* __restrict__ A,
            const unsigned short* __restrict__ Bw,
            float* __restrict__ Cf,
            unsigned short* __restrict__ Qo,
            unsigned short* __restrict__ Ko,
            unsigned short* __restrict__ Vo,
            int M, int N, int K, int Lseq) {
  __shared__ unsigned short Al[2][128 * 64];       // 2 x 16KB
  __shared__ unsigned short Bl[2][NF * 64 * 64];   // 2 x NF*8KB
  const int tid = threadIdx.x;
  const int lane = tid & 63, w = tid >> 6;
  const int wm = w >> 2, wn = w & 3;
  const int g4 = lane >> 4, r16 = lane & 15;
  const long arow0 = (long)blockIdx.y * 128;
  const long brow0 = (long)blockIdx.x * (NF * 64);

#define VMNF                                                                  \
  do {                                                                        \
    if constexpr (NF == 3) asm volatile("s_waitcnt vmcnt(3)" ::: "memory");   \
    else                   asm volatile("s_waitcnt vmcnt(4)" ::: "memory");   \
  } while (0)

  auto lda = [&](int db, int mf, int ks) -> bf16x8 {
    return *(const bf16x8*)((const char*)&Al[db][0] +
                            ((wm * 64 + mf * 16 + r16) << 7) +
                            (((ks * 4 + g4) ^ (r16 & 7)) << 4));
  };
  auto ldb = [&](int db, int nf, int ks) -> bf16x8 {
    return *(const bf16x8*)((const char*)&Bl[db][0] +
                            ((wn * (NF * 16) + nf * 16 + r16) << 7) +
                            (((ks * 4 + g4) ^ (r16 & 7)) << 4));
  };
  auto stgA = [&](int db, int kt) {
#pragma unroll
    for (int c_ = 0; c_ < 2; ++c_) {
      int off_ = (c_ << 13) + (tid << 4);
      int row_ = off_ >> 7;
      int cbs_ = ((off_ >> 4) & 7) ^ (row_ & 7);
      gload_lds16(A + (arow0 + row_) * (long)K + (kt << 6) + cbs_ * 8,
                  (char*)&Al[db][0] + off_);
    }
  };
  auto stgB = [&](int db, int kt) {
#pragma unroll
    for (int c_ = 0; c_ < NF; ++c_) {
      int off_ = (c_ << 13) + (tid << 4);
      int row_ = off_ >> 7;
      int cbs_ = ((off_ >> 4) & 7) ^ (row_ & 7);
      gload_lds16(Bw + (brow0 + row_) * (long)K + (kt << 6) + cbs_ * 8,
                  (char*)&Bl[db][0] + off_);
    }
  };

  f32x4 acc[4][NF];
#pragma unroll
  for (int i = 0; i < 4; ++i)
#pragma unroll
    for (int j = 0; j < NF; ++j) acc[i][j] = (f32x4){0.f, 0.f, 0.f, 0.f};

  bf16x8 breg[NF][2];
  bf16x8 aX[2][2], aY[2][2];

  auto loadB = [&](int db) {
#pragma unroll
    for (int nf = 0; nf < NF; ++nf)
#pragma unroll
      for (int ks = 0; ks < 2; ++ks) breg[nf][ks] = ldb(db, nf, ks);
  };
  auto prefA = [&](bf16x8 (&dst)[2][2], int db, int q) {
#pragma unroll
    for (int mf = 0; mf < 2; ++mf)
#pragma unroll
      for (int ks = 0; ks < 2; ++ks) dst[mf][ks] = lda(db, 2 * q + mf, ks);
  };
  auto mfq = [&](int q, bf16x8 (&af)[2][2]) {
    __builtin_amdgcn_s_setprio(1);
#pragma unroll
    for (int mf = 0; mf < 2; ++mf)
#pragma unroll
      for (int nf = 0; nf < NF; ++nf) {
        acc[2 * q + mf][nf] = MF(af[mf][0], breg[nf][0], acc[2 * q + mf][nf]);
        acc[2 * q + mf][nf] = MF(af[mf][1], breg[nf][1], acc[2 * q + mf][nf]);
      }
    __builtin_amdgcn_s_setprio(0);
  };

  const int NT = K >> 6;
  stgB(0, 0); stgA(0, 0); stgB(1, 1);
  VMNF;
  BAR;
  loadB(0);
  prefA(aX, 0, 0);

  for (int i = 0; i < (NT >> 1); ++i) {
    const int t1 = 2 * i + 1;
    int t2 = 2 * i + 2; if (t2 > NT - 1) t2 = NT - 1;
    int t3 = 2 * i + 3; if (t3 > NT - 1) t3 = NT - 1;
    stgA(1, t1);
    BAR;
    mfq(0, aX);
    prefA(aY, 0, 1);
    BAR;
    stgB(0, t2);
    VMNF;
    BAR;
    mfq(1, aY);
    loadB(1);
    prefA(aX, 1, 0);
    BAR;
    stgA(0, t2);
    BAR;
    mfq(0, aX);
    prefA(aY, 1, 1);
    BAR;
    stgB(1, t3);
    VMNF;
    BAR;
    mfq(1, aY);
    loadB(0);
    prefA(aX, 0, 0);
    BAR;
  }
  asm volatile("s_waitcnt vmcnt(0)" ::: "memory");

  const float qscale = 0.08838834764831845f;  // 1/sqrt(128) folded into Q
#pragma unroll
  for (int mf = 0; mf < 4; ++mf) {
#pragma unroll
    for (int nf = 0; nf < NF; ++nf) {
#pragma unroll
      for (int i = 0; i < 4; ++i) {
        long row = arow0 + wm * 64 + mf * 16 + 4 * g4 + i;
        long col = brow0 + wn * (NF * 16) + nf * 16 + r16;
        float v = acc[mf][nf][i];
        if (EPI == 0) {
          Cf[row * N + col] = v;
        } else {
          int which = (int)(col >> 11);
          int h = ((int)col >> 7) & 15;
          int d = (int)col & 127;
          int b = (int)(row >> 11);
          int l = (int)row & 2047;
          long bhead = (long)(b * 16 + h);
          if (which == 0)
            Qo[(bhead * Lseq + l) * 128 + d] = f2bf(v * qscale);
          else if (which == 1)
            Ko[(bhead * Lseq + l) * 128 + d] = f2bf(v);
          else
            Vo[(bhead * 128 + d) * Lseq + l] = f2bf(v);
        }
      }
    }
  }
#undef VMNF
}

// ---------------------------------------------------------------------------
// Flash attention (causal) v6: round-12 dataflow + V-fragment hoist
// (measured: attn ~64us).
// ---------------------------------------------------------------------------
__global__ __launch_bounds__(256, 2)
void attn_fwd(const unsigned short* __restrict__ Q,
              const unsigned short* __restrict__ K,
              const unsigned short* __restrict__ Vt,
              unsigned short* __restrict__ Y, int L) {
  const int D = 128;
  const int id = blockIdx.x;
  const int g = id & 7, kk = id >> 3;
  const int bh = (g << 2) + (kk >> 5);
  const int qt = 31 - (kk & 31);
  const int tid = threadIdx.x, lane = tid & 63, w = tid >> 6;
  const int g4 = lane >> 4, r16 = lane & 15;
  const int q0 = qt * 64;

  __shared__ unsigned short Klds[2 * 64 * 128];
  __shared__ unsigned short Vlds[2 * 128 * 64];
  __shared__ unsigned short P[4][16][64];
  __shared__ float corrS[4][16];
  __shared__ float lrunS[4][16];

  const unsigned short* Qh = Q + (long)bh * L * D;
  const unsigned short* Kh = K + (long)bh * L * D;
  const unsigned short* Vh = Vt + (long)bh * D * L;

#define STAGE_TILE(kt_, buf_)                                                 \
  do {                                                                        \
    const int kbase_ = (kt_) * 64;                                            \
    _Pragma("unroll")                                                         \
    for (int r_ = 0; r_ < 4; ++r_) {                                          \
      int off_ = (tid << 4) + (r_ << 12);                                     \
      int krow_ = off_ >> 8, kcb_ = (off_ >> 4) & 15;                         \
      int kcbs_ = kcb_ ^ (krow_ & 7);                                         \
      gload_lds16(Kh + (long)(kbase_ + krow_) * 128 + kcbs_ * 8,              \
                  (char*)Klds + (buf_)*16384 + (w << 10) + (r_ << 12));       \
      int vrow_ = off_ >> 7, vcb_ = (off_ >> 4) & 7;                          \
      int vcbs_ = vcb_ ^ (vrow_ & 7);                                         \
      gload_lds16(Vh + (long)vrow_ * L + kbase_ + vcbs_ * 8,                  \
                  (char*)Vlds + (buf_)*16384 + (w << 10) + (r_ << 12));       \
    }                                                                         \
  } while (0)

  bf16x8 qf[4];
  {
    long qrow = q0 + 16 * w + r16;
#pragma unroll
    for (int ks = 0; ks < 4; ++ks)
      qf[ks] = *(const bf16x8*)(Qh + qrow * D + ks * 32 + g4 * 8);
  }
  f32x4 o[8];
#pragma unroll
  for (int j = 0; j < 8; ++j) o[j] = (f32x4){0.f, 0.f, 0.f, 0.f};
  float mrun = -1e30f, lrun = 0.f;
  const int qg = q0 + 16 * w + r16;
  char* Pl = (char*)&P[w][0][0];

  int cur = 0;
  STAGE_TILE(0, 0);

  for (int kt = 0; kt <= qt; ++kt) {
    if (kt < qt) {
      STAGE_TILE(kt + 1, cur ^ 1);
      asm volatile("s_waitcnt vmcnt(8)" ::: "memory");
    } else {
      asm volatile("s_waitcnt vmcnt(0)" ::: "memory");
    }
    __builtin_amdgcn_s_barrier();

    const char* Kl = (const char*)Klds + cur * 16384;
    const char* Vl = (const char*)Vlds + cur * 16384;

    f32x4 s[4];
#pragma unroll
    for (int nf = 0; nf < 4; ++nf) s[nf] = (f32x4){0.f, 0.f, 0.f, 0.f};
#pragma unroll
    for (int ks = 0; ks < 4; ++ks) {
#pragma unroll
      for (int nf = 0; nf < 4; ++nf) {
        int row = 16 * nf + r16;
        bf16x8 kf = *(const bf16x8*)(Kl + row * 256 +
                                     (((ks * 4 + g4) ^ (row & 7)) << 4));
        s[nf] = MF(kf, qf[ks], s[nf]);
      }
    }

    // V-hoist: issue all 16 V ds_reads now; softmax hides their latency.
    bf16x8 vfr[2][8];
#pragma unroll
    for (int ks2 = 0; ks2 < 2; ++ks2)
#pragma unroll
      for (int nf2 = 0; nf2 < 8; ++nf2) {
        int row = 16 * nf2 + r16;
        vfr[ks2][nf2] = *(const bf16x8*)(Vl + row * 128 +
                                         (((ks2 * 4 + g4) ^ (row & 7)) << 4));
      }

    const bool diag = (kt == qt);
    float rmax = -1e30f;
#pragma unroll
    for (int nf = 0; nf < 4; ++nf)
#pragma unroll
      for (int i = 0; i < 4; ++i) {
        float t = s[nf][i];
        if (diag && (kt * 64 + 16 * nf + 4 * g4 + i) > qg) t = -1e30f;
        s[nf][i] = t;
        rmax = fmaxf(rmax, t);
      }
    rmax = fmaxf(rmax, __shfl_xor(rmax, 16));
    rmax = fmaxf(rmax, __shfl_xor(rmax, 32));

    const bool full = __any(rmax > mrun + 8.0f);
    float corr = 1.f;
    if (full) {
      float mnew = fmaxf(mrun, rmax);
      corr = __expf(mrun - mnew);
      mrun = mnew;
      if (g4 == 0) corrS[w][r16] = corr;
    }

    float rs = 0.f;
#pragma unroll
    for (int nf = 0; nf < 4; ++nf) {
      float p0 = __expf(s[nf][0] - mrun);
      float p1 = __expf(s[nf][1] - mrun);
      float p2 = __expf(s[nf][2] - mrun);
      float p3 = __expf(s[nf][3] - mrun);
      rs += (p0 + p1) + (p2 + p3);
      ushort4 pw;
      pw.x = f2bf(p0); pw.y = f2bf(p1); pw.z = f2bf(p2); pw.w = f2bf(p3);
      *(ushort4*)(Pl + r16 * 128 + (((2 * nf + (g4 >> 1)) ^ (r16 & 7)) << 4) +
                  ((g4 & 1) << 3)) = pw;
    }
    rs += __shfl_xor(rs, 16);
    rs += __shfl_xor(rs, 32);
    lrun = lrun * corr + rs;

    if (full) {
#pragma unroll
      for (int i = 0; i < 4; ++i) {
        float cb = corrS[w][4 * g4 + i];
#pragma unroll
        for (int nf2 = 0; nf2 < 8; ++nf2) o[nf2][i] *= cb;
      }
    }

#pragma unroll
    for (int ks2 = 0; ks2 < 2; ++ks2) {
      bf16x8 pf = *(const bf16x8*)(Pl + r16 * 128 +
                                   (((ks2 * 4 + g4) ^ (r16 & 7)) << 4));
#pragma unroll
      for (int nf2 = 0; nf2 < 8; ++nf2)
        o[nf2] = MF(pf, vfr[ks2][nf2], o[nf2]);
    }
    FENCE;
    __builtin_amdgcn_s_barrier();
    cur ^= 1;
  }
#undef STAGE_TILE

  if (g4 == 0) lrunS[w][r16] = lrun;
  const int b = bh >> 4, h = bh & 15;
#pragma unroll
  for (int i = 0; i < 4; ++i) {
    float linv = 1.f / lrunS[w][4 * g4 + i];
#pragma unroll
    for (int nf2 = 0; nf2 < 8; ++nf2) {
      long row = (long)b * L + q0 + 16 * w + 4 * g4 + i;
      Y[row * 2048 + h * 128 + 16 * nf2 + r16] = f2bf(o[nf2][i] * linv);
    }
  }
}

// ---------------------------------------------------------------------------
extern "C" void kernel_launch(void* const* d_in, const int* in_sizes, int n_in,
                              void* d_out, int out_size, void* d_ws,
                              size_t ws_size, hipStream_t stream) {
  const float* x = (const float*)d_in[0];
  const float* wa = (const float*)d_in[1];
  const float* wp = (const float*)d_in[2];
  float* out = (float*)d_out;
  const int B = 2, L = 2048, C = 2048;
  const int M = B * L;  // 4096

  unsigned short* xb = (unsigned short*)d_ws;
  unsigned short* wab = xb + (size_t)M * C;
  unsigned short* wpb = wab + (size_t)3 * C * C;
  unsigned short* Qb = wpb + (size_t)C * C;
  unsigned short* Kb = Qb + (size_t)M * C;
  unsigned short* Vb = Kb + (size_t)M * C;
  unsigned short* Yb = Vb + (size_t)M * C;

  const int n1 = M * C / 4;
  const int n2 = n1 + 3 * C * C / 4;
  const int n4 = n2 + C * C / 4;
  cast_all<<<2048, 256, 0, stream>>>(x, wa, wp, xb, wab, wpb, n1, n2, n4);

  // qkv: 128x192 (NF=3), 80KB LDS -> 2 blocks/CU, grid 32x32 = 1024 blocks
  gemm8p<1, 3><<<dim3(3 * C / 192, M / 128), 512, 0, stream>>>(
      xb, wab, nullptr, Qb, Kb, Vb, M, 3 * C, C, L);

  // attn: QBLK=64, 4 waves, 1024 blocks (2 blocks/CU), V-hoist
  attn_fwd<<<1024, 256, 0, stream>>>(Qb, Kb, Vb, Yb, L);

  // proj: 128x256 (NF=4), grid 8x32 = 256 blocks = exactly 1 round
  gemm8p<0, 4><<<dim3(C / 256, M / 128), 512, 0, stream>>>(
      Yb, wpb, out, nullptr, nullptr, nullptr, M, C, C, L);
}